// Round 8
// baseline (55.022 us; speedup 1.0000x reference)
//
#include <hip/hip_runtime.h>
#include <stdint.h>

#define D_DIM 2048
#define B_DIM 4096
#define BMT 128                       // output tile M = N
#define BKB 128                       // K step in BYTES (= 128 fp8 elements)
#define NKS (B_DIM / 128)             // 32 K-steps total
#define NSPL 6                        // K-splits per pair
#define NTILE (D_DIM / BMT)           // 16
#define NPAIR ((NTILE * (NTILE + 1)) / 2)  // 136 upper-triangle tile pairs
#define GRAM_BLOCKS (NPAIR * NSPL)    // 816 = 8 XCDs x 102; 3.2 blocks/CU (5/CU LDS cap)
#define MWORDS (D_DIM / 64)           // 32 mask words per row
#define NT32 (D_DIM / 64)             // 32 row-blocks for mask part
#define MPAIR ((NT32 * (NT32 + 1)) / 2)  // 528 upper mask block pairs
#define TP_BLOCKS ((D_DIM / 64) * (B_DIM / 64))  // 2048 transpose blocks

typedef __attribute__((ext_vector_type(4))) float f32x4;
typedef __attribute__((ext_vector_type(4))) int   i32x4;
typedef __attribute__((ext_vector_type(8))) int   i32x8;

__device__ __forceinline__ void gload16(const void* g, void* lds) {
    __builtin_amdgcn_global_load_lds((__attribute__((address_space(1))) void*)g,
                                     (__attribute__((address_space(3))) void*)lds,
                                     16, 0, 0);
}

// Fused prep: transpose X -> fp8 XT (blocks [0, TP_BLOCKS)) and build the packed
// upper-triangle mask + per-block edge counts (blocks [TP_BLOCKS, TP_BLOCKS+MPAIR)).
// Block 0 zero-inits gsum/ticket (kernel-boundary ordering makes zeros visible to gram).
// NO memset node (r6/r7 evidence: tiny hipMemsetAsync graph node cost ~9 us of critical path).
__global__ __launch_bounds__(256) void prep_kernel(
    const float* __restrict__ X, const float* __restrict__ ddi,
    unsigned char* __restrict__ XT8, unsigned long long* __restrict__ mask64,
    int* __restrict__ partials, float* __restrict__ gsum, int* __restrict__ ticket)
{
    __shared__ float tile[64][65];
    __shared__ int redi[4];
    const int tid = threadIdx.x;

    if (blockIdx.x < TP_BLOCKS) {
        // ---- transpose + f32->fp8(e4m3, RNE) ----
        if (blockIdx.x == 0 && tid == 0) { *gsum = 0.f; *ticket = 0; }
        const int i0 = (blockIdx.x & 31) * 64;   // D/64 = 32 column blocks of X
        const int k0 = (blockIdx.x >> 5) * 64;   // row block of X

        const int c4 = tid & 15;
        const int rr = tid >> 4;
        #pragma unroll
        for (int p = 0; p < 4; ++p) {
            const int kr = p * 16 + rr;
            const float4 v = *reinterpret_cast<const float4*>(
                &X[(size_t)(k0 + kr) * D_DIM + i0 + c4 * 4]);
            tile[kr][c4 * 4 + 0] = v.x;
            tile[kr][c4 * 4 + 1] = v.y;
            tile[kr][c4 * 4 + 2] = v.z;
            tile[kr][c4 * 4 + 3] = v.w;
        }
        __syncthreads();

        const int ir16 = tid >> 4;
        const int kq   = tid & 15;
        #pragma unroll
        for (int pi = 0; pi < 4; ++pi) {
            const int ir = pi * 16 + ir16;
            const int kc = kq * 4;
            int pk = __builtin_amdgcn_cvt_pk_fp8_f32(tile[kc + 0][ir], tile[kc + 1][ir], 0, false);
            pk     = __builtin_amdgcn_cvt_pk_fp8_f32(tile[kc + 2][ir], tile[kc + 3][ir], pk, true);
            *reinterpret_cast<int*>(XT8 + (size_t)(i0 + ir) * B_DIM + k0 + kc) = pk;
        }
    } else {
        // ---- mask: bit (i,j) = (i<j) && (ddi[i][j]>0 || ddi[j][i]>0), 64x64 block pairs bi<=bj ----
        const int mb = blockIdx.x - TP_BLOCKS;
        int bi = 0, rem = mb;
        while (rem >= NT32 - bi) { rem -= NT32 - bi; ++bi; }
        const int bj = bi + rem;
        const int r0 = bi * 64;
        const int c0 = bj * 64;

        const int c4 = tid & 15;
        const int rr = tid >> 4;
        #pragma unroll
        for (int p = 0; p < 4; ++p) {
            const int kr = p * 16 + rr;
            const float4 v = *reinterpret_cast<const float4*>(
                &ddi[(size_t)(c0 + kr) * D_DIM + r0 + c4 * 4]);
            tile[kr][c4 * 4 + 0] = v.x;
            tile[kr][c4 * 4 + 1] = v.y;
            tile[kr][c4 * 4 + 2] = v.z;
            tile[kr][c4 * 4 + 3] = v.w;
        }
        __syncthreads();

        const int lane = tid & 63;
        const int w    = tid >> 6;
        int cnt = 0;
        #pragma unroll
        for (int rr2 = 0; rr2 < 16; ++rr2) {
            const int li = w * 16 + rr2;
            const int gi = r0 + li;
            const int gj = c0 + lane;
            const float a  = ddi[(size_t)gi * D_DIM + c0 + lane];  // coalesced row read
            const float at = tile[lane][li];                       // ddi[gj][gi]
            const bool bit = (gi < gj) && (a > 0.f || at > 0.f);
            const unsigned long long word = __ballot(bit);
            if (lane == 0) mask64[(size_t)gi * MWORDS + bj] = word;
            cnt += bit ? 1 : 0;
        }
        #pragma unroll
        for (int off = 32; off > 0; off >>= 1) cnt += __shfl_down(cnt, off, 64);
        if (lane == 0) redi[w] = cnt;
        __syncthreads();
        if (tid == 0) partials[mb] = redi[0] + redi[1] + redi[2] + redi[3];  // race-free, rewritten every call
    }
}

// Read one 32-byte (K=128-slice) MX-MFMA fragment from the XOR-swizzled LDS tile.
// Lane's 32 B = granules {2g, 2g+1} of row; swizzle maps them to slots {s, s^1}
// (adjacency preserved since XOR acts identically on both). 2x ds_read_b128, 2-way banks.
__device__ __forceinline__ i32x8 frag_read(const unsigned char* ls, int row, int g) {
    const int s = (2 * g) ^ (row & 7);
    const i32x4 lo = *reinterpret_cast<const i32x4*>(ls + row * BKB + s * 16);
    const i32x4 hi = *reinterpret_cast<const i32x4*>(ls + row * BKB + (s ^ 1) * 16);
    i32x8 r;
    r[0] = lo[0]; r[1] = lo[1]; r[2] = lo[2]; r[3] = lo[3];
    r[4] = hi[0]; r[5] = hi[1]; r[6] = hi[2]; r[7] = hi[3];
    return r;
}

// Gram = XT8_panel_i · XT8_panel_j^T, MX-scaled fp8 e4m3 (unit scales), K=128/MFMA.
// r5-proven structure: 128x128 tile, 4 waves (2x2 of 64x64), SINGLE-buffered 32 KiB LDS
// (4-5 blocks/CU — implicit cross-block pipelining per m114; explicit dbuf at 2/CU
// REGRESSED, r7 + m132/m230 evidence), 2 barriers/K-step, gload16 staging with
// (row&7) 16B-granule XOR swizzle [rule #21]. Grid 816 = 136 pairs x 6 K-splits,
// XCD-chunked bijective ordering (816 = 8 x 102). Self-finalizing via device-scope
// ticket: last block sums mask partials + computes out = gsum/(B*max(cnt,1)).
__global__ __launch_bounds__(256) void gram_masked_kernel(
    const unsigned char* __restrict__ XT8,
    const unsigned long long* __restrict__ mask64,
    const int* __restrict__ partials,
    float* __restrict__ gsum, int* __restrict__ ticket,
    float* __restrict__ out)
{
    __shared__ __align__(16) unsigned char lsA[BMT * BKB];   // 16 KiB
    __shared__ __align__(16) unsigned char lsB[BMT * BKB];   // 16 KiB
    __shared__ float redf[4];
    __shared__ int redi[4];
    __shared__ int lastFlag;

    const int tid  = threadIdx.x;
    const int lane = tid & 63;
    const int w    = tid >> 6;        // wave 0..3
    const int wr   = w >> 1, wc = w & 1;
    const int m16  = lane & 15;
    const int g    = lane >> 4;       // k-group 0..3 (32 B each of the 128 B row)

    // XCD-chunked bijective ordering: XCD (bid%8) covers logical chunk of 102.
    const int bid = blockIdx.x;
    const int logical = (bid & 7) * (GRAM_BLOCKS / 8) + (bid >> 3);
    const int pair = logical / NSPL;          // ti-major pair order
    const int s    = logical % NSPL;

    int ti = 0, rem = pair;
    while (rem >= NTILE - ti) { rem -= NTILE - ti; ++ti; }
    const int tj = ti + rem;
    const int i0 = ti * BMT, j0 = tj * BMT;

    const int ks0 = (NKS * s) / NSPL;         // K-step range [ks0, ks1), 5-6 steps
    const int ks1 = (NKS * (s + 1)) / NSPL;
    const int nkt = ks1 - ks0;
    const int kbase = ks0 * BKB;              // byte offset into the 4096-byte K row

    f32x4 acc[4][4];
    #pragma unroll
    for (int a = 0; a < 4; ++a)
        #pragma unroll
        for (int b = 0; b < 4; ++b)
            acc[a][b] = (f32x4){0.f, 0.f, 0.f, 0.f};

    // Staging: chunk = p*256 + tid; 16B granules, row = chunk/8 (8 granules per 128 B row).
    // Linear LDS dest + inverse-swizzled global source: slot (row,c) gets granule (row, c^(row&7)).
    size_t gaoff[4], gboff[4];
    #pragma unroll
    for (int p = 0; p < 4; ++p) {
        const int chunk = p * 256 + tid;
        const int row = chunk >> 3;
        const int sc = (chunk & 7) ^ (row & 7);
        gaoff[p] = (size_t)(i0 + row) * B_DIM + kbase + sc * 16;
        gboff[p] = (size_t)(j0 + row) * B_DIM + kbase + sc * 16;
    }
    char* lbaseA = (char*)lsA + (size_t)w * 1024;   // wave-uniform segment base
    char* lbaseB = (char*)lsB + (size_t)w * 1024;

    for (int kt = 0; kt < nkt; ++kt) {
        const int koff = kt * BKB;
        #pragma unroll
        for (int p = 0; p < 4; ++p) {
            gload16(XT8 + gaoff[p] + koff, lbaseA + p * 4096);
            gload16(XT8 + gboff[p] + koff, lbaseB + p * 4096);
        }
        __syncthreads();   // drains vmcnt (LDS tiles ready)

        i32x8 aF[4], bF[4];
        #pragma unroll
        for (int f = 0; f < 4; ++f) {
            aF[f] = frag_read(lsA, wr * 64 + f * 16 + m16, g);
            bF[f] = frag_read(lsB, wc * 64 + f * 16 + m16, g);
        }
        #pragma unroll
        for (int fi = 0; fi < 4; ++fi)
            #pragma unroll
            for (int fj = 0; fj < 4; ++fj)
                acc[fi][fj] = __builtin_amdgcn_mfma_scale_f32_16x16x128_f8f6f4(
                    aF[fi], bF[fj], acc[fi][fj],
                    0 /*A fmt: fp8 e4m3*/, 0 /*B fmt: fp8 e4m3*/,
                    0, 0x7F7F7F7F /*A scales = 1.0*/,
                    0, 0x7F7F7F7F /*B scales = 1.0*/);

        __syncthreads();   // all waves done reading before next-stage overwrite
    }

    // Fused epilogue: masked sum from packed bits (mask encodes i<j already).
    // C/D layout: col = lane&15, row = (lane>>4)*4 + reg  [m89/m91; shape-determined]
    // Guard: words entirely below the diagonal are unwritten (poison) — skip them.
    float lsum = 0.f;
    const int jb = (j0 + wc * 64) >> 6;
    #pragma unroll
    for (int fi = 0; fi < 4; ++fi) {
        #pragma unroll
        for (int r = 0; r < 4; ++r) {
            const int i = i0 + wr * 64 + fi * 16 + g * 4 + r;
            unsigned long long wword = 0ull;
            if (jb * 64 + 63 > i) wword = mask64[(size_t)i * MWORDS + jb];
            #pragma unroll
            for (int fj = 0; fj < 4; ++fj) {
                if ((wword >> (fj * 16 + m16)) & 1ull) lsum += acc[fi][fj][r];
            }
        }
    }
    #pragma unroll
    for (int off = 32; off > 0; off >>= 1) lsum += __shfl_down(lsum, off, 64);
    if (lane == 0) redf[w] = lsum;
    __syncthreads();

    // Ticketed finalize: the last block to arrive sums partials + computes the output.
    if (tid == 0) {
        atomicAdd(gsum, redf[0] + redf[1] + redf[2] + redf[3]);
        __threadfence();                         // order gsum add before ticket
        const int old = atomicAdd(ticket, 1);    // device-scope
        lastFlag = (old == GRAM_BLOCKS - 1);
    }
    __syncthreads();
    if (lastFlag) {                               // block-uniform
        int sc = 0;
        for (int i = tid; i < MPAIR; i += 256) sc += partials[i];
        #pragma unroll
        for (int off = 32; off > 0; off >>= 1) sc += __shfl_down(sc, off, 64);
        if (lane == 0) redi[w] = sc;
        __syncthreads();
        if (tid == 0) {
            __threadfence();
            const float s2  = atomicAdd(gsum, 0.0f); // coherent read of all blocks' adds
            const int   cnt = redi[0] + redi[1] + redi[2] + redi[3];
            out[0] = s2 / ((float)B_DIM * fmaxf((float)cnt, 1.0f));
        }
    }
}

extern "C" void kernel_launch(void* const* d_in, const int* in_sizes, int n_in,
                              void* d_out, int out_size, void* d_ws, size_t ws_size,
                              hipStream_t stream) {
    const float* X   = (const float*)d_in[0];   // drug_probs (B_DIM x D_DIM)
    const float* ddi = (const float*)d_in[1];   // ddi_matrix (D_DIM x D_DIM)
    float* out = (float*)d_out;

    const size_t XT_BYTES   = (size_t)D_DIM * B_DIM;                                // 8 MiB fp8
    const size_t MASK_BYTES = (size_t)D_DIM * MWORDS * sizeof(unsigned long long);  // 512 KiB
    const size_t PART_BYTES = (size_t)MPAIR * sizeof(int);
    if (ws_size < XT_BYTES + MASK_BYTES + PART_BYTES + 64) return;

    unsigned char* XT8 = (unsigned char*)d_ws;
    unsigned long long* mask64 = (unsigned long long*)((char*)d_ws + XT_BYTES);
    int*   partials = (int*)((char*)d_ws + XT_BYTES + MASK_BYTES);
    char*  ctrl     = (char*)d_ws + XT_BYTES + MASK_BYTES + PART_BYTES;
    float* gsum     = (float*)(ctrl + 0);
    int*   ticket   = (int*)(ctrl + 4);

    prep_kernel<<<TP_BLOCKS + MPAIR, 256, 0, stream>>>(X, ddi, XT8, mask64, partials, gsum, ticket);
    gram_masked_kernel<<<GRAM_BLOCKS, 256, 0, stream>>>(XT8, mask64, partials, gsum, ticket, out);
}

// Round 9
// 38.844 us; speedup vs baseline: 1.4165x; 1.4165x over previous
//
#include <hip/hip_runtime.h>
#include <stdint.h>

#define D_DIM 2048
#define B_DIM 4096
#define BMT 128                       // output tile M = N
#define BKB 128                       // K step in BYTES (= 256 fp4 elements)
#define ROWB (B_DIM / 2)              // 2048 bytes per XT4 row
#define NKS4 (B_DIM / 256)            // 16 K-steps total (256 fp4 elems each)
#define NSPL 6                        // K-splits per pair
#define NTILE (D_DIM / BMT)           // 16
#define NPAIR ((NTILE * (NTILE + 1)) / 2)  // 136 upper-triangle tile pairs
#define GRAM_BLOCKS (NPAIR * NSPL)    // 816 = 8 XCDs x 102
#define MWORDS (D_DIM / 64)           // 32 mask words per row
#define NT32 (D_DIM / 64)             // 32 row-blocks for mask part
#define MPAIR ((NT32 * (NT32 + 1)) / 2)  // 528 upper mask block pairs
#define TP_BLOCKS ((D_DIM / 64) * (B_DIM / 64))  // 2048 transpose blocks

typedef __attribute__((ext_vector_type(4))) float f32x4;
typedef __attribute__((ext_vector_type(4))) int   i32x4;
typedef __attribute__((ext_vector_type(8))) int   i32x8;

__device__ __forceinline__ void gload16(const void* g, void* lds) {
    __builtin_amdgcn_global_load_lds((__attribute__((address_space(1))) void*)g,
                                     (__attribute__((address_space(3))) void*)lds,
                                     16, 0, 0);
}

// Fused prep: transpose X -> fp4 XT (blocks [0, TP_BLOCKS)) and build the packed
// upper-triangle mask + per-block edge counts (blocks [TP_BLOCKS, TP_BLOCKS+MPAIR)).
// Block 0 zero-inits gsum (kernel-boundary ordering makes the zero visible to gram).
// fp4 path: y = 4*x quantized RNE onto the e2m1 grid {0,.5,1,1.5,2,3,4}; the MFMA
// applies scale 2^-2 to BOTH operands (4*4*2^-4 = 1 exact). All-positive inputs.
__global__ __launch_bounds__(256) void prep_kernel(
    const float* __restrict__ X, const float* __restrict__ ddi,
    unsigned char* __restrict__ XT4, unsigned long long* __restrict__ mask64,
    int* __restrict__ partials, float* __restrict__ gsum)
{
    __shared__ float tile[64][65];
    __shared__ int redi[4];
    const int tid = threadIdx.x;

    if (blockIdx.x < TP_BLOCKS) {
        // ---- transpose + f32 -> fp4(e2m1, RNE on 4x grid) ----
        if (blockIdx.x == 0 && tid == 0) *gsum = 0.f;
        const int i0 = (blockIdx.x & 31) * 64;   // D/64 = 32 column blocks of X
        const int k0 = (blockIdx.x >> 5) * 64;   // row block of X

        const int c4 = tid & 15;
        const int rr = tid >> 4;
        #pragma unroll
        for (int p = 0; p < 4; ++p) {
            const int kr = p * 16 + rr;
            const float4 v = *reinterpret_cast<const float4*>(
                &X[(size_t)(k0 + kr) * D_DIM + i0 + c4 * 4]);
            tile[kr][c4 * 4 + 0] = v.x;
            tile[kr][c4 * 4 + 1] = v.y;
            tile[kr][c4 * 4 + 2] = v.z;
            tile[kr][c4 * 4 + 3] = v.w;
        }
        __syncthreads();

        // each thread packs 8 consecutive k-nibbles for one row; 2 passes x 32 rows
        const int kq8 = tid & 7;          // k-group of 8
        const int irr = tid >> 3;         // 0..31
        #pragma unroll
        for (int p = 0; p < 2; ++p) {
            const int ir = p * 32 + irr;
            unsigned int pk = 0;
            #pragma unroll
            for (int e = 0; e < 8; ++e) {
                const float y = 4.0f * tile[kq8 * 8 + e][ir];
                // monotone code 0..6 = RNE to {0,0.5,1,1.5,2,3,4} (y in [0,4))
                const unsigned int c = (unsigned)(y >= 0.25f) + (unsigned)(y >= 0.75f)
                                     + (unsigned)(y >= 1.25f) + (unsigned)(y >= 1.75f)
                                     + (unsigned)(y >= 2.5f)  + (unsigned)(y >= 3.5f);
                pk |= c << (4 * e);
            }
            *reinterpret_cast<unsigned int*>(
                XT4 + (size_t)(i0 + ir) * ROWB + (k0 >> 1) + kq8 * 4) = pk;
        }
    } else {
        // ---- mask: bit (i,j) = (i<j) && (ddi[i][j]>0 || ddi[j][i]>0), 64x64 block pairs bi<=bj ----
        const int mb = blockIdx.x - TP_BLOCKS;
        int bi = 0, rem = mb;
        while (rem >= NT32 - bi) { rem -= NT32 - bi; ++bi; }
        const int bj = bi + rem;
        const int r0 = bi * 64;
        const int c0 = bj * 64;

        const int c4 = tid & 15;
        const int rr = tid >> 4;
        #pragma unroll
        for (int p = 0; p < 4; ++p) {
            const int kr = p * 16 + rr;
            const float4 v = *reinterpret_cast<const float4*>(
                &ddi[(size_t)(c0 + kr) * D_DIM + r0 + c4 * 4]);
            tile[kr][c4 * 4 + 0] = v.x;
            tile[kr][c4 * 4 + 1] = v.y;
            tile[kr][c4 * 4 + 2] = v.z;
            tile[kr][c4 * 4 + 3] = v.w;
        }
        __syncthreads();

        const int lane = tid & 63;
        const int w    = tid >> 6;
        int cnt = 0;
        #pragma unroll
        for (int rr2 = 0; rr2 < 16; ++rr2) {
            const int li = w * 16 + rr2;
            const int gi = r0 + li;
            const int gj = c0 + lane;
            const float a  = ddi[(size_t)gi * D_DIM + c0 + lane];  // coalesced row read
            const float at = tile[lane][li];                       // ddi[gj][gi]
            const bool bit = (gi < gj) && (a > 0.f || at > 0.f);
            const unsigned long long word = __ballot(bit);
            if (lane == 0) mask64[(size_t)gi * MWORDS + bj] = word;
            cnt += bit ? 1 : 0;
        }
        #pragma unroll
        for (int off = 32; off > 0; off >>= 1) cnt += __shfl_down(cnt, off, 64);
        if (lane == 0) redi[w] = cnt;
        __syncthreads();
        if (tid == 0) partials[mb] = redi[0] + redi[1] + redi[2] + redi[3];  // race-free
    }
}

// Read one 16-byte (K=128 fp4) MX-MFMA fragment from the XOR-swizzled LDS tile.
// Row = 128 B = 256 fp4; chunk c in {0,1} selects K-half; lane group g takes granule
// 4c+g, swizzled by row. ONE ds_read_b128 per fragment. Upper 4 dwords unused for fp4.
__device__ __forceinline__ i32x8 frag_read4(const unsigned char* ls, int row, int g, int c) {
    const int s = (4 * c + g) ^ (row & 7);
    const i32x4 lo = *reinterpret_cast<const i32x4*>(ls + row * BKB + s * 16);
    i32x8 r = {lo[0], lo[1], lo[2], lo[3], 0, 0, 0, 0};
    return r;
}

// Gram = XT4_panel_i · XT4_panel_j^T, MX-scaled fp4 e2m1, scale 2^-2 both sides,
// K=128/MFMA, 2 chunks per 128-B K-step (256 elems). r5-PROVEN structure otherwise:
// 128x128 tile, 4 waves (2x2 of 64x64), SINGLE-buffered 32 KiB LDS (~4 blocks/CU,
// implicit cross-block pipelining per m114), 2 barriers/K-step, gload16 staging with
// (row&7) 16B-granule XOR swizzle [rule #21]. Grid 816 = 136 pairs x 6 K-splits
// (nkt 2-3 of the 16 quarter-K steps), XCD-chunked bijective ordering (816 = 8x102).
// NO in-kernel finalize (r8 evidence: per-block threadfence+ticket cost ~10 us).
__global__ __launch_bounds__(256) void gram_masked_kernel(
    const unsigned char* __restrict__ XT4,
    const unsigned long long* __restrict__ mask64,
    float* __restrict__ gsum)
{
    __shared__ __align__(16) unsigned char lsA[BMT * BKB];   // 16 KiB
    __shared__ __align__(16) unsigned char lsB[BMT * BKB];   // 16 KiB
    __shared__ float redf[4];

    const int tid  = threadIdx.x;
    const int lane = tid & 63;
    const int w    = tid >> 6;        // wave 0..3
    const int wr   = w >> 1, wc = w & 1;
    const int m16  = lane & 15;
    const int g    = lane >> 4;       // k-group 0..3

    // XCD-chunked bijective ordering: XCD (bid%8) covers logical chunk of 102.
    const int bid = blockIdx.x;
    const int logical = (bid & 7) * (GRAM_BLOCKS / 8) + (bid >> 3);
    const int pair = logical / NSPL;          // ti-major pair order
    const int s    = logical % NSPL;

    int ti = 0, rem = pair;
    while (rem >= NTILE - ti) { rem -= NTILE - ti; ++ti; }
    const int tj = ti + rem;
    const int i0 = ti * BMT, j0 = tj * BMT;

    const int ks0 = (NKS4 * s) / NSPL;        // K-step range [ks0, ks1), 2-3 steps
    const int ks1 = (NKS4 * (s + 1)) / NSPL;
    const int nkt = ks1 - ks0;
    const int kbase = ks0 * BKB;              // byte offset into the 2048-byte K row

    f32x4 acc[4][4];
    #pragma unroll
    for (int a = 0; a < 4; ++a)
        #pragma unroll
        for (int b = 0; b < 4; ++b)
            acc[a][b] = (f32x4){0.f, 0.f, 0.f, 0.f};

    // Staging: chunk = p*256 + tid; 16B granules, row = chunk/8 (8 granules per 128 B row).
    // Linear LDS dest + inverse-swizzled global source: slot (row,c) gets granule (row, c^(row&7)).
    size_t gaoff[4], gboff[4];
    #pragma unroll
    for (int p = 0; p < 4; ++p) {
        const int chunk = p * 256 + tid;
        const int row = chunk >> 3;
        const int sc = (chunk & 7) ^ (row & 7);
        gaoff[p] = (size_t)(i0 + row) * ROWB + kbase + sc * 16;
        gboff[p] = (size_t)(j0 + row) * ROWB + kbase + sc * 16;
    }
    char* lbaseA = (char*)lsA + (size_t)w * 1024;   // wave-uniform segment base
    char* lbaseB = (char*)lsB + (size_t)w * 1024;

    for (int kt = 0; kt < nkt; ++kt) {
        const int koff = kt * BKB;
        #pragma unroll
        for (int p = 0; p < 4; ++p) {
            gload16(XT4 + gaoff[p] + koff, lbaseA + p * 4096);
            gload16(XT4 + gboff[p] + koff, lbaseB + p * 4096);
        }
        __syncthreads();   // drains vmcnt (LDS tiles ready)

        #pragma unroll
        for (int c = 0; c < 2; ++c) {             // two K=128 chunks per 128-B row
            i32x8 aF[4], bF[4];
            #pragma unroll
            for (int f = 0; f < 4; ++f) {
                aF[f] = frag_read4(lsA, wr * 64 + f * 16 + m16, g, c);
                bF[f] = frag_read4(lsB, wc * 64 + f * 16 + m16, g, c);
            }
            #pragma unroll
            for (int fi = 0; fi < 4; ++fi)
                #pragma unroll
                for (int fj = 0; fj < 4; ++fj)
                    acc[fi][fj] = __builtin_amdgcn_mfma_scale_f32_16x16x128_f8f6f4(
                        aF[fi], bF[fj], acc[fi][fj],
                        4 /*A fmt: fp4 e2m1*/, 4 /*B fmt: fp4 e2m1*/,
                        0, 0x7D7D7D7D /*A scales = 2^-2*/,
                        0, 0x7D7D7D7D /*B scales = 2^-2*/);
        }

        __syncthreads();   // all waves done reading before next-stage overwrite
    }

    // Fused epilogue: masked sum from packed bits (mask encodes i<j already).
    // C/D layout: col = lane&15, row = (lane>>4)*4 + reg  [m89/m91; shape-determined]
    // Guard: words entirely below the diagonal are unwritten (poison) — skip them.
    float lsum = 0.f;
    const int jb = (j0 + wc * 64) >> 6;
    #pragma unroll
    for (int fi = 0; fi < 4; ++fi) {
        #pragma unroll
        for (int r = 0; r < 4; ++r) {
            const int i = i0 + wr * 64 + fi * 16 + g * 4 + r;
            unsigned long long wword = 0ull;
            if (jb * 64 + 63 > i) wword = mask64[(size_t)i * MWORDS + jb];
            #pragma unroll
            for (int fj = 0; fj < 4; ++fj) {
                if ((wword >> (fj * 16 + m16)) & 1ull) lsum += acc[fi][fj][r];
            }
        }
    }
    #pragma unroll
    for (int off = 32; off > 0; off >>= 1) lsum += __shfl_down(lsum, off, 64);
    if (lane == 0) redf[w] = lsum;
    __syncthreads();
    if (tid == 0) atomicAdd(gsum, redf[0] + redf[1] + redf[2] + redf[3]);
}

__global__ __launch_bounds__(256) void finalize_kernel(
    const float* __restrict__ gsum, const int* __restrict__ partials,
    float* __restrict__ out)
{
    __shared__ int redi[4];
    const int tid = threadIdx.x;
    int s = 0;
    for (int i = tid; i < MPAIR; i += 256) s += partials[i];
    #pragma unroll
    for (int off = 32; off > 0; off >>= 1) s += __shfl_down(s, off, 64);
    const int lane = tid & 63, w = tid >> 6;
    if (lane == 0) redi[w] = s;
    __syncthreads();
    if (tid == 0) {
        const int cnt = redi[0] + redi[1] + redi[2] + redi[3];
        out[0] = gsum[0] / ((float)B_DIM * fmaxf((float)cnt, 1.0f));
    }
}

extern "C" void kernel_launch(void* const* d_in, const int* in_sizes, int n_in,
                              void* d_out, int out_size, void* d_ws, size_t ws_size,
                              hipStream_t stream) {
    const float* X   = (const float*)d_in[0];   // drug_probs (B_DIM x D_DIM)
    const float* ddi = (const float*)d_in[1];   // ddi_matrix (D_DIM x D_DIM)
    float* out = (float*)d_out;

    const size_t XT_BYTES   = (size_t)D_DIM * ROWB;                                 // 4 MiB fp4
    const size_t MASK_BYTES = (size_t)D_DIM * MWORDS * sizeof(unsigned long long);  // 512 KiB
    const size_t PART_BYTES = (size_t)MPAIR * sizeof(int);
    if (ws_size < XT_BYTES + MASK_BYTES + PART_BYTES + 64) return;

    unsigned char* XT4 = (unsigned char*)d_ws;
    unsigned long long* mask64 = (unsigned long long*)((char*)d_ws + XT_BYTES);
    int*   partials = (int*)((char*)d_ws + XT_BYTES + MASK_BYTES);
    float* gsum     = (float*)((char*)d_ws + XT_BYTES + MASK_BYTES + PART_BYTES);

    prep_kernel<<<TP_BLOCKS + MPAIR, 256, 0, stream>>>(X, ddi, XT4, mask64, partials, gsum);
    gram_masked_kernel<<<GRAM_BLOCKS, 256, 0, stream>>>(XT4, mask64, gsum);
    finalize_kernel<<<1, 256, 0, stream>>>(gsum, partials, out);
}

// Round 10
// 37.592 us; speedup vs baseline: 1.4637x; 1.0333x over previous
//
#include <hip/hip_runtime.h>
#include <stdint.h>

#define D_DIM 2048
#define B_DIM 4096
#define BMT 128                       // output tile M = N
#define BKB 128                       // K step in BYTES (= 256 fp4 elements)
#define ROWB (B_DIM / 2)              // 2048 bytes per XT4 row
#define NKS4 (B_DIM / 256)            // 16 K-steps total (256 fp4 elems each)
#define NTILE (D_DIM / BMT)           // 16
#define NPAIR ((NTILE * (NTILE + 1)) / 2)  // 136 upper-triangle tile pairs
// Non-uniform K-split: 104 pairs x 4 + 32 pairs x 3 = 512 blocks = EXACTLY 2/CU,
// zero-tail packing (r9's 816 = 3x256+48 wasted a 81%-idle dispatch round).
#define P4 104
#define GRAM_BLOCKS (P4 * 4 + (NPAIR - P4) * 3)   // 512 = 8 XCDs x 64
#define MWORDS (D_DIM / 64)           // 32 mask words per row
#define NT32 (D_DIM / 64)             // 32 row-blocks for mask part
#define MPAIR ((NT32 * (NT32 + 1)) / 2)  // 528 upper mask block pairs
#define TP_BLOCKS ((D_DIM / 64) * (B_DIM / 64))  // 2048 transpose blocks

typedef __attribute__((ext_vector_type(4))) float f32x4;
typedef __attribute__((ext_vector_type(4))) int   i32x4;
typedef __attribute__((ext_vector_type(8))) int   i32x8;

__device__ __forceinline__ void gload16(const void* g, void* lds) {
    __builtin_amdgcn_global_load_lds((__attribute__((address_space(1))) void*)g,
                                     (__attribute__((address_space(3))) void*)lds,
                                     16, 0, 0);
}

// Fused prep: transpose X -> fp4 XT (blocks [0, TP_BLOCKS)) and build the packed
// upper-triangle mask + per-block edge counts (blocks [TP_BLOCKS, TP_BLOCKS+MPAIR)).
// Block 0 zero-inits gsum (kernel-boundary ordering makes the zero visible to gram).
// fp4 path: y = 4*x quantized RNE onto the e2m1 grid {0,.5,1,1.5,2,3,4}; the MFMA
// applies scale 2^-2 to BOTH operands (4*4*2^-4 = 1 exact). All-positive inputs.
__global__ __launch_bounds__(256) void prep_kernel(
    const float* __restrict__ X, const float* __restrict__ ddi,
    unsigned char* __restrict__ XT4, unsigned long long* __restrict__ mask64,
    int* __restrict__ partials, float* __restrict__ gsum)
{
    __shared__ float tile[64][65];
    __shared__ int redi[4];
    const int tid = threadIdx.x;

    if (blockIdx.x < TP_BLOCKS) {
        // ---- transpose + f32 -> fp4(e2m1, RNE on 4x grid) ----
        if (blockIdx.x == 0 && tid == 0) *gsum = 0.f;
        const int i0 = (blockIdx.x & 31) * 64;   // D/64 = 32 column blocks of X
        const int k0 = (blockIdx.x >> 5) * 64;   // row block of X

        const int c4 = tid & 15;
        const int rr = tid >> 4;
        #pragma unroll
        for (int p = 0; p < 4; ++p) {
            const int kr = p * 16 + rr;
            const float4 v = *reinterpret_cast<const float4*>(
                &X[(size_t)(k0 + kr) * D_DIM + i0 + c4 * 4]);
            tile[kr][c4 * 4 + 0] = v.x;
            tile[kr][c4 * 4 + 1] = v.y;
            tile[kr][c4 * 4 + 2] = v.z;
            tile[kr][c4 * 4 + 3] = v.w;
        }
        __syncthreads();

        // each thread packs 8 consecutive k-nibbles for one row; 2 passes x 32 rows
        const int kq8 = tid & 7;          // k-group of 8
        const int irr = tid >> 3;         // 0..31
        #pragma unroll
        for (int p = 0; p < 2; ++p) {
            const int ir = p * 32 + irr;
            unsigned int pk = 0;
            #pragma unroll
            for (int e = 0; e < 8; ++e) {
                const float y = 4.0f * tile[kq8 * 8 + e][ir];
                // monotone code 0..6 = RNE to {0,0.5,1,1.5,2,3,4} (y in [0,4))
                const unsigned int c = (unsigned)(y >= 0.25f) + (unsigned)(y >= 0.75f)
                                     + (unsigned)(y >= 1.25f) + (unsigned)(y >= 1.75f)
                                     + (unsigned)(y >= 2.5f)  + (unsigned)(y >= 3.5f);
                pk |= c << (4 * e);
            }
            *reinterpret_cast<unsigned int*>(
                XT4 + (size_t)(i0 + ir) * ROWB + (k0 >> 1) + kq8 * 4) = pk;
        }
    } else {
        // ---- mask: bit (i,j) = (i<j) && (ddi[i][j]>0 || ddi[j][i]>0), 64x64 block pairs bi<=bj ----
        const int mb = blockIdx.x - TP_BLOCKS;
        int bi = 0, rem = mb;
        while (rem >= NT32 - bi) { rem -= NT32 - bi; ++bi; }
        const int bj = bi + rem;
        const int r0 = bi * 64;
        const int c0 = bj * 64;

        const int c4 = tid & 15;
        const int rr = tid >> 4;
        #pragma unroll
        for (int p = 0; p < 4; ++p) {
            const int kr = p * 16 + rr;
            const float4 v = *reinterpret_cast<const float4*>(
                &ddi[(size_t)(c0 + kr) * D_DIM + r0 + c4 * 4]);
            tile[kr][c4 * 4 + 0] = v.x;
            tile[kr][c4 * 4 + 1] = v.y;
            tile[kr][c4 * 4 + 2] = v.z;
            tile[kr][c4 * 4 + 3] = v.w;
        }
        __syncthreads();

        const int lane = tid & 63;
        const int w    = tid >> 6;
        int cnt = 0;
        #pragma unroll
        for (int rr2 = 0; rr2 < 16; ++rr2) {
            const int li = w * 16 + rr2;
            const int gi = r0 + li;
            const int gj = c0 + lane;
            const float a  = ddi[(size_t)gi * D_DIM + c0 + lane];  // coalesced row read
            const float at = tile[lane][li];                       // ddi[gj][gi]
            const bool bit = (gi < gj) && (a > 0.f || at > 0.f);
            const unsigned long long word = __ballot(bit);
            if (lane == 0) mask64[(size_t)gi * MWORDS + bj] = word;
            cnt += bit ? 1 : 0;
        }
        #pragma unroll
        for (int off = 32; off > 0; off >>= 1) cnt += __shfl_down(cnt, off, 64);
        if (lane == 0) redi[w] = cnt;
        __syncthreads();
        if (tid == 0) partials[mb] = redi[0] + redi[1] + redi[2] + redi[3];  // race-free
    }
}

// Read one 16-byte (K=128 fp4) MX-MFMA fragment from the XOR-swizzled LDS tile.
// Row = 128 B = 256 fp4; chunk c in {0,1} selects K-half; lane group g takes granule
// 4c+g, swizzled by row. ONE ds_read_b128 per fragment. Upper 4 dwords unused for fp4.
__device__ __forceinline__ i32x8 frag_read4(const unsigned char* ls, int row, int g, int c) {
    const int s = (4 * c + g) ^ (row & 7);
    const i32x4 lo = *reinterpret_cast<const i32x4*>(ls + row * BKB + s * 16);
    i32x8 r = {lo[0], lo[1], lo[2], lo[3], 0, 0, 0, 0};
    return r;
}

// Gram = XT4_panel_i · XT4_panel_j^T, MX-scaled fp4 e2m1, scale 2^-2 both sides,
// K=128/MFMA, 2 chunks per 128-B K-step (256 elems). r9-PROVEN loop structure:
// 128x128 tile, 4 waves (2x2 of 64x64), SINGLE-buffered 32 KiB LDS (implicit
// cross-block pipelining per m114; dbuf regressed, r7 + m132/m230), 2 barriers/K-step,
// gload16 staging with (row&7) 16B-granule XOR swizzle [rule #21].
// Grid 512 = 104 pairs x 4 + 32 x 3 K-splits (nkt 4-6) = EXACTLY 2 blocks/CU,
// zero-tail; XCD-chunked bijective ordering (512 = 8 x 64).
__global__ __launch_bounds__(256) void gram_masked_kernel(
    const unsigned char* __restrict__ XT4,
    const unsigned long long* __restrict__ mask64,
    float* __restrict__ gsum)
{
    __shared__ __align__(16) unsigned char lsA[BMT * BKB];   // 16 KiB
    __shared__ __align__(16) unsigned char lsB[BMT * BKB];   // 16 KiB
    __shared__ float redf[4];

    const int tid  = threadIdx.x;
    const int lane = tid & 63;
    const int w    = tid >> 6;        // wave 0..3
    const int wr   = w >> 1, wc = w & 1;
    const int m16  = lane & 15;
    const int g    = lane >> 4;       // k-group 0..3

    // XCD-chunked bijective ordering: XCD (bid%8) covers logical chunk of 64.
    const int bid = blockIdx.x;
    const int logical = (bid & 7) * (GRAM_BLOCKS / 8) + (bid >> 3);

    // Non-uniform K-split decode: first 104 pairs -> 4 splits, rest -> 3.
    int pair, s, ns;
    if (logical < P4 * 4) { pair = logical >> 2; s = logical & 3; ns = 4; }
    else { const int t = logical - P4 * 4; pair = P4 + t / 3; s = t % 3; ns = 3; }

    int ti = 0, rem = pair;
    while (rem >= NTILE - ti) { rem -= NTILE - ti; ++ti; }
    const int tj = ti + rem;
    const int i0 = ti * BMT, j0 = tj * BMT;

    const int ks0 = (NKS4 * s) / ns;          // K-step range [ks0, ks1): 4 or 5-6 steps
    const int ks1 = (NKS4 * (s + 1)) / ns;
    const int nkt = ks1 - ks0;
    const int kbase = ks0 * BKB;              // byte offset into the 2048-byte K row

    f32x4 acc[4][4];
    #pragma unroll
    for (int a = 0; a < 4; ++a)
        #pragma unroll
        for (int b = 0; b < 4; ++b)
            acc[a][b] = (f32x4){0.f, 0.f, 0.f, 0.f};

    // Staging: chunk = p*256 + tid; 16B granules, row = chunk/8 (8 granules per 128 B row).
    // Linear LDS dest + inverse-swizzled global source: slot (row,c) gets granule (row, c^(row&7)).
    size_t gaoff[4], gboff[4];
    #pragma unroll
    for (int p = 0; p < 4; ++p) {
        const int chunk = p * 256 + tid;
        const int row = chunk >> 3;
        const int sc = (chunk & 7) ^ (row & 7);
        gaoff[p] = (size_t)(i0 + row) * ROWB + kbase + sc * 16;
        gboff[p] = (size_t)(j0 + row) * ROWB + kbase + sc * 16;
    }
    char* lbaseA = (char*)lsA + (size_t)w * 1024;   // wave-uniform segment base
    char* lbaseB = (char*)lsB + (size_t)w * 1024;

    for (int kt = 0; kt < nkt; ++kt) {
        const int koff = kt * BKB;
        #pragma unroll
        for (int p = 0; p < 4; ++p) {
            gload16(XT4 + gaoff[p] + koff, lbaseA + p * 4096);
            gload16(XT4 + gboff[p] + koff, lbaseB + p * 4096);
        }
        __syncthreads();   // drains vmcnt (LDS tiles ready)

        #pragma unroll
        for (int c = 0; c < 2; ++c) {             // two K=128 chunks per 128-B row
            i32x8 aF[4], bF[4];
            #pragma unroll
            for (int f = 0; f < 4; ++f) {
                aF[f] = frag_read4(lsA, wr * 64 + f * 16 + m16, g, c);
                bF[f] = frag_read4(lsB, wc * 64 + f * 16 + m16, g, c);
            }
            #pragma unroll
            for (int fi = 0; fi < 4; ++fi)
                #pragma unroll
                for (int fj = 0; fj < 4; ++fj)
                    acc[fi][fj] = __builtin_amdgcn_mfma_scale_f32_16x16x128_f8f6f4(
                        aF[fi], bF[fj], acc[fi][fj],
                        4 /*A fmt: fp4 e2m1*/, 4 /*B fmt: fp4 e2m1*/,
                        0, 0x7D7D7D7D /*A scales = 2^-2*/,
                        0, 0x7D7D7D7D /*B scales = 2^-2*/);
        }

        __syncthreads();   // all waves done reading before next-stage overwrite
    }

    // Fused epilogue: masked sum from packed bits (mask encodes i<j already).
    // C/D layout: col = lane&15, row = (lane>>4)*4 + reg  [m89/m91; shape-determined]
    // Guard: words entirely below the diagonal are unwritten (poison) — skip them.
    float lsum = 0.f;
    const int jb = (j0 + wc * 64) >> 6;
    #pragma unroll
    for (int fi = 0; fi < 4; ++fi) {
        #pragma unroll
        for (int r = 0; r < 4; ++r) {
            const int i = i0 + wr * 64 + fi * 16 + g * 4 + r;
            unsigned long long wword = 0ull;
            if (jb * 64 + 63 > i) wword = mask64[(size_t)i * MWORDS + jb];
            #pragma unroll
            for (int fj = 0; fj < 4; ++fj) {
                if ((wword >> (fj * 16 + m16)) & 1ull) lsum += acc[fi][fj][r];
            }
        }
    }
    #pragma unroll
    for (int off = 32; off > 0; off >>= 1) lsum += __shfl_down(lsum, off, 64);
    if (lane == 0) redf[w] = lsum;
    __syncthreads();
    if (tid == 0) atomicAdd(gsum, redf[0] + redf[1] + redf[2] + redf[3]);
}

__global__ __launch_bounds__(256) void finalize_kernel(
    const float* __restrict__ gsum, const int* __restrict__ partials,
    float* __restrict__ out)
{
    __shared__ int redi[4];
    const int tid = threadIdx.x;
    int s = 0;
    for (int i = tid; i < MPAIR; i += 256) s += partials[i];
    #pragma unroll
    for (int off = 32; off > 0; off >>= 1) s += __shfl_down(s, off, 64);
    const int lane = tid & 63, w = tid >> 6;
    if (lane == 0) redi[w] = s;
    __syncthreads();
    if (tid == 0) {
        const int cnt = redi[0] + redi[1] + redi[2] + redi[3];
        out[0] = gsum[0] / ((float)B_DIM * fmaxf((float)cnt, 1.0f));
    }
}

extern "C" void kernel_launch(void* const* d_in, const int* in_sizes, int n_in,
                              void* d_out, int out_size, void* d_ws, size_t ws_size,
                              hipStream_t stream) {
    const float* X   = (const float*)d_in[0];   // drug_probs (B_DIM x D_DIM)
    const float* ddi = (const float*)d_in[1];   // ddi_matrix (D_DIM x D_DIM)
    float* out = (float*)d_out;

    const size_t XT_BYTES   = (size_t)D_DIM * ROWB;                                 // 4 MiB fp4
    const size_t MASK_BYTES = (size_t)D_DIM * MWORDS * sizeof(unsigned long long);  // 512 KiB
    const size_t PART_BYTES = (size_t)MPAIR * sizeof(int);
    if (ws_size < XT_BYTES + MASK_BYTES + PART_BYTES + 64) return;

    unsigned char* XT4 = (unsigned char*)d_ws;
    unsigned long long* mask64 = (unsigned long long*)((char*)d_ws + XT_BYTES);
    int*   partials = (int*)((char*)d_ws + XT_BYTES + MASK_BYTES);
    float* gsum     = (float*)((char*)d_ws + XT_BYTES + MASK_BYTES + PART_BYTES);

    prep_kernel<<<TP_BLOCKS + MPAIR, 256, 0, stream>>>(X, ddi, XT4, mask64, partials, gsum);
    gram_masked_kernel<<<GRAM_BLOCKS, 256, 0, stream>>>(XT4, mask64, gsum);
    finalize_kernel<<<1, 256, 0, stream>>>(gsum, partials, out);
}